// Round 14
// baseline (978.314 us; speedup 1.0000x reference)
//
#include <hip/hip_runtime.h>
#include <math.h>
#include <stdint.h>

#define B_   2
#define S_   40
#define P_   780
#define L_   512
#define C_   64
#define FF_  256
#define NTOK (B_*P_*L_)   // 798720

typedef __attribute__((ext_vector_type(8))) short short8;
typedef __attribute__((ext_vector_type(4))) float f32x4;
typedef __attribute__((ext_vector_type(4))) unsigned short us4;

// ---------- helpers ----------
__device__ __forceinline__ float ln64(float r, float g, float b) {
    float s1 = r, s2 = r * r;
    #pragma unroll
    for (int m = 1; m < 64; m <<= 1) {
        s1 += __shfl_xor(s1, m, 64);
        s2 += __shfl_xor(s2, m, 64);
    }
    float mu  = s1 * (1.0f / 64.0f);
    float var = s2 * (1.0f / 64.0f) - mu * mu;
    return (r - mu) * rsqrtf(var + 1e-5f) * g + b;
}
__device__ __forceinline__ float gelu_fast(float x) {
    float x2 = x * x;
    float u  = x * fmaf(0.044715f, x2, 1.0f);
    float e  = __builtin_amdgcn_exp2f(u * 2.302265106f);
    return x * e * __builtin_amdgcn_rcpf(e + 1.0f);
}
__device__ __forceinline__ float softplus_f(float v) {
    return (v > 20.0f) ? v : log1pf(__expf(v));
}
__device__ __forceinline__ float elup1(float v) {
    return (v > 0.0f) ? v + 1.0f : __expf(v);
}
__device__ __forceinline__ unsigned short f2bf(float f) {
    union { float f; uint32_t u; } cv; cv.f = f;
    uint32_t u = cv.u;
    return (unsigned short)((u + 0x7FFFu + ((u >> 16) & 1u)) >> 16);  // RNE
}
__device__ __forceinline__ float bf2f(unsigned short u) {
    union { uint32_t u; float f; } cv; cv.u = (uint32_t)u << 16; return cv.f;
}
__device__ __forceinline__ float bflo(uint32_t w) {
    union { uint32_t u; float f; } cv; cv.u = w << 16; return cv.f;
}
__device__ __forceinline__ float bfhi(uint32_t w) {
    union { uint32_t u; float f; } cv; cv.u = w & 0xffff0000u; return cv.f;
}
__device__ __forceinline__ uint32_t cvtpk(float a, float b) {
    uint32_t d;
    asm("v_cvt_pk_bf16_f32 %0, %1, %2" : "=v"(d) : "v"(a), "v"(b));
    return d;
}

// ---------- 1. input 1x1 conv 22->64 + ReLU ----------
__global__ void k_conv_in(const float* __restrict__ x, const float* __restrict__ w_in,
                          const float* __restrict__ b_in, float* __restrict__ h) {
    int gid = blockIdx.x * 256 + threadIdx.x;
    int c  = gid & 63;
    int tk = gid >> 6;
    if (tk >= B_ * L_ * S_) return;
    int b = tk / (L_ * S_);
    int r = tk % (L_ * S_);
    int l = r / S_;
    int s = r % S_;
    float acc = b_in[c];
    const float* xb = x + (size_t)b * 22 * L_ * S_ + (size_t)l * S_ + s;
    #pragma unroll
    for (int cc = 0; cc < 22; cc++)
        acc = fmaf(xb[(size_t)cc * L_ * S_], w_in[c * 22 + cc], acc);
    h[gid] = fmaxf(acc, 0.0f);
}

// ---------- 2. seq2pair gather + LN -> hp (bf16, row layout) ----------
__global__ void k_gather_ln(const float* __restrict__ h, const float* __restrict__ g0,
                            const float* __restrict__ be0, unsigned short* __restrict__ hp) {
    int lane = threadIdx.x & 63;
    int wv   = threadIdx.x >> 6;
    int tk = blockIdx.x * 4 + wv;
    if (tk >= NTOK) return;
    int b = tk / (P_ * L_);
    int r = tk % (P_ * L_);
    int p = r / L_;
    int l = r % L_;
    int i = 0, rem = p, cnt = S_ - 1;
    while (rem >= cnt) { rem -= cnt; cnt--; i++; }
    int j = i + 1 + rem;
    const float* hb = h + (((size_t)b * L_ + l) * S_) * 64;
    float v = hb[i * 64 + lane] + hb[j * 64 + lane];
    hp[(size_t)tk * 64 + lane] = f2bf(ln64(v, g0[lane], be0[lane]));
}

// ---------- 3a. QKV weight pre-swizzle into MFMA A-fragment layout (bf16) ----------
__global__ void k_wprep_qkv(const float* __restrict__ rqw, const float* __restrict__ rkw,
                            const float* __restrict__ rvw, const float* __restrict__ cqw,
                            const float* __restrict__ ckw, const float* __restrict__ cvw,
                            unsigned short* __restrict__ qkvf) {
    int g = blockIdx.x * 256 + threadIdx.x;   // < 6144
    if (g >= 6144) return;
    int m = g >> 9, r = g & 511;
    int mat = m >> 1, layer = m & 1;
    int q = r >> 6, lane = r & 63;
    int c = lane & 15, hi = lane >> 4;
    int nt = q >> 1, s = q & 1;
    const float* base;
    switch (mat) {
        case 0: base = rqw; break; case 1: base = rkw; break; case 2: base = rvw; break;
        case 3: base = cqw; break; case 4: base = ckw; break; default: base = cvw; break;
    }
    const float* src = base + layer * 4096 + (nt * 16 + c) * 64 + s * 32 + hi * 8;
    short8 v;
    #pragma unroll
    for (int i = 0; i < 8; i++) v[i] = (short)f2bf(src[i]);
    *(short8*)(qkvf + (size_t)m * 4096 + (size_t)r * 8) = v;
}

// ---------- 3b. FFN weight pre-swizzle ----------
__global__ void k_wprep(const float* __restrict__ f1w, const float* __restrict__ f2w,
                        unsigned short* __restrict__ w1s, unsigned short* __restrict__ w2s) {
    int g = blockIdx.x * 256 + threadIdx.x;   // [0, 8192)
    if (g >= 8192) return;
    int layer = g >> 12;
    int rem   = g & 4095;
    int which = rem >> 11;
    int idx   = rem & 2047;
    int l  = idx & 63;
    int q  = idx >> 6;
    int c  = l & 15, hi = l >> 4;
    const float* src;
    unsigned short* dst;
    if (which == 0) {
        int s = q & 1, nt = q >> 1;
        src = f1w + (size_t)layer * 16384 + (nt * 16 + c) * 64 + s * 32 + hi * 8;
        dst = w1s + (size_t)layer * 16384 + (size_t)idx * 8;
    } else {
        int s = q & 7, nt = q >> 3;
        src = f2w + (size_t)layer * 16384 + (nt * 16 + c) * 256 + s * 32 + hi * 8;
        dst = w2s + (size_t)layer * 16384 + (size_t)idx * 8;
    }
    short8 v;
    #pragma unroll
    for (int i = 0; i < 8; i++) v[i] = (short)f2bf(src[i]);
    *(short8*)dst = v;
}

// ---------- 4. FUSED row attention (reduction + map), hp -> hpT ----------
__global__ __launch_bounds__(512) void k_row_fused(
        const unsigned short* __restrict__ hp, unsigned short* __restrict__ hpT,
        const unsigned short* __restrict__ wqf, const unsigned short* __restrict__ wkf,
        const unsigned short* __restrict__ wvf,
        const float* __restrict__ bq, const float* __restrict__ bk,
        const float* __restrict__ bv, const float* __restrict__ wp,
        const float* __restrict__ bp, const float* __restrict__ lng,
        const float* __restrict__ lnb) {
    __shared__ float redK[8][64];
    __shared__ float redV[8][64];
    __shared__ float kvfin[64];
    __shared__ float sksum[64];
    __shared__ float swkv[256];

    const int tid = threadIdx.x, lane = tid & 63, w8 = tid >> 6;
    const int t = lane & 15, hi = lane >> 4;
    const int slice = blockIdx.x;                  // b*P + p
    const size_t base = (size_t)slice * L_ * 64;

    short8 xkeep[4][2];
    float ks[4][4] = {}, kv[4][4] = {};
    {
        short8 wkfr[4][2], wvfr[4][2];
        #pragma unroll
        for (int nt = 0; nt < 4; nt++)
            #pragma unroll
            for (int s = 0; s < 2; s++) {
                wkfr[nt][s] = *(const short8*)(wkf + ((size_t)((nt*2+s)*64 + lane)) * 8);
                wvfr[nt][s] = *(const short8*)(wvf + ((size_t)((nt*2+s)*64 + lane)) * 8);
            }
        f32x4 bkL[4], bvL[4];
        #pragma unroll
        for (int nt = 0; nt < 4; nt++) {
            bkL[nt] = *(const f32x4*)(bk + nt * 16 + hi * 4);
            bvL[nt] = *(const f32x4*)(bv + nt * 16 + hi * 4);
        }
        #pragma unroll
        for (int it = 0; it < 4; it++) {
            int tok = (w8 + it * 8) * 16 + t;
            const unsigned short* src = hp + base + (size_t)tok * 64;
            #pragma unroll
            for (int s = 0; s < 2; s++)
                xkeep[it][s] = *(const short8*)(src + s * 32 + hi * 8);
            f32x4 aK[4], aV[4];
            #pragma unroll
            for (int nt = 0; nt < 4; nt++) { aK[nt] = (f32x4){0,0,0,0}; aV[nt] = (f32x4){0,0,0,0}; }
            __builtin_amdgcn_s_setprio(1);
            #pragma unroll
            for (int nt = 0; nt < 4; nt++)
                #pragma unroll
                for (int s = 0; s < 2; s++) {
                    aK[nt] = __builtin_amdgcn_mfma_f32_16x16x32_bf16(wkfr[nt][s], xkeep[it][s], aK[nt], 0, 0, 0);
                    aV[nt] = __builtin_amdgcn_mfma_f32_16x16x32_bf16(wvfr[nt][s], xkeep[it][s], aV[nt], 0, 0, 0);
                }
            __builtin_amdgcn_s_setprio(0);
            #pragma unroll
            for (int nt = 0; nt < 4; nt++) {
                float kk[4], vv[4];
                #pragma unroll
                for (int r = 0; r < 4; r++) {
                    kk[r] = elup1(aK[nt][r] + bkL[nt][r]);
                    vv[r] = aV[nt][r] + bvL[nt][r];
                }
                float sp = kk[0] + kk[1] + kk[2] + kk[3];
                sp += __shfl_xor(sp, 16, 64);
                sp += __shfl_xor(sp, 32, 64);
                #pragma unroll
                for (int r = 0; r < 4; r++) { ks[nt][r] += kk[r]; kv[nt][r] += sp * vv[r]; }
            }
        }
    }
    #pragma unroll
    for (int nt = 0; nt < 4; nt++)
        #pragma unroll
        for (int r = 0; r < 4; r++) {
            #pragma unroll
            for (int m = 1; m < 16; m <<= 1) {
                ks[nt][r] += __shfl_xor(ks[nt][r], m, 64);
                kv[nt][r] += __shfl_xor(kv[nt][r], m, 64);
            }
        }
    if (t == 0) {
        #pragma unroll
        for (int nt = 0; nt < 4; nt++)
            #pragma unroll
            for (int r = 0; r < 4; r++) {
                redK[w8][nt * 16 + hi * 4 + r] = ks[nt][r];
                redV[w8][nt * 16 + hi * 4 + r] = kv[nt][r];
            }
    }
    __syncthreads();
    if (tid < 64) {
        float a = 0.0f, b2 = 0.0f;
        #pragma unroll
        for (int w = 0; w < 8; w++) { a += redK[w][tid]; b2 += redV[w][tid]; }
        sksum[tid] = a;
        kvfin[tid] = b2;
    }
    __syncthreads();
    if (tid < 256) {
        int c = tid & 63, n = tid >> 6;
        const float* wpr = wp + c * 64 + n * 16;
        float s = 0.0f;
        #pragma unroll
        for (int e = 0; e < 16; e++) s = fmaf(kvfin[n * 16 + e], wpr[e], s);
        swkv[c * 4 + n] = s;
    }
    __syncthreads();

    short8 wqfr[4][2];
    #pragma unroll
    for (int nt = 0; nt < 4; nt++)
        #pragma unroll
        for (int s = 0; s < 2; s++)
            wqfr[nt][s] = *(const short8*)(wqf + ((size_t)((nt*2+s)*64 + lane)) * 8);
    f32x4 bqL[4], bpL[4], gL[4], bL[4];
    #pragma unroll
    for (int nt = 0; nt < 4; nt++) {
        bqL[nt] = *(const f32x4*)(bq + nt * 16 + hi * 4);
        bpL[nt] = *(const f32x4*)(bp + nt * 16 + hi * 4);
        gL[nt]  = *(const f32x4*)(lng + nt * 16 + hi * 4);
        bL[nt]  = *(const f32x4*)(lnb + nt * 16 + hi * 4);
    }
    const int bb = slice / P_, pp = slice - bb * P_;

    #pragma unroll
    for (int it = 0; it < 4; it++) {
        int tok = (w8 + it * 8) * 16 + t;
        f32x4 aQ[4];
        #pragma unroll
        for (int nt = 0; nt < 4; nt++) aQ[nt] = (f32x4){0,0,0,0};
        __builtin_amdgcn_s_setprio(1);
        #pragma unroll
        for (int nt = 0; nt < 4; nt++)
            #pragma unroll
            for (int s = 0; s < 2; s++)
                aQ[nt] = __builtin_amdgcn_mfma_f32_16x16x32_bf16(wqfr[nt][s], xkeep[it][s], aQ[nt], 0, 0, 0);
        __builtin_amdgcn_s_setprio(0);
        float z[4];
        #pragma unroll
        for (int nt = 0; nt < 4; nt++) {
            f32x4 kS = *(const f32x4*)(sksum + nt * 16 + hi * 4);
            float d = 0.0f;
            #pragma unroll
            for (int r = 0; r < 4; r++)
                d = fmaf(elup1(aQ[nt][r] + bqL[nt][r]), kS[r], d);
            d += __shfl_xor(d, 16, 64);
            d += __shfl_xor(d, 32, 64);
            z[nt] = 1.0f / (d + 1e-6f);
        }
        const unsigned short* srcr = hp + base + (size_t)tok * 64;
        float o[4][4];
        float s1 = 0.0f, s2 = 0.0f;
        #pragma unroll
        for (int nt = 0; nt < 4; nt++) {
            us4 xr4 = *(const us4*)(srcr + nt * 16 + hi * 4);
            #pragma unroll
            for (int r = 0; r < 4; r++) {
                int ch = nt * 16 + hi * 4 + r;
                f32x4 wv4 = *(const f32x4*)(swkv + ch * 4);
                float val = z[0] * wv4[0] + z[1] * wv4[1] + z[2] * wv4[2] + z[3] * wv4[3]
                          + bpL[nt][r] + bf2f(xr4[r]);
                o[nt][r] = val;
                s1 += val; s2 += val * val;
            }
        }
        s1 += __shfl_xor(s1, 16, 64);  s1 += __shfl_xor(s1, 32, 64);
        s2 += __shfl_xor(s2, 16, 64);  s2 += __shfl_xor(s2, 32, 64);
        float mu  = s1 * (1.0f / 64.0f);
        float var = s2 * (1.0f / 64.0f) - mu * mu;
        float rs  = rsqrtf(var + 1e-5f);
        unsigned short* dst = hpT + (((size_t)bb * L_ + tok) * P_ + pp) * 64;
        #pragma unroll
        for (int nt = 0; nt < 4; nt++) {
            float r0 = (o[nt][0] - mu) * rs * gL[nt][0] + bL[nt][0];
            float r1 = (o[nt][1] - mu) * rs * gL[nt][1] + bL[nt][1];
            float r2 = (o[nt][2] - mu) * rs * gL[nt][2] + bL[nt][2];
            float r3 = (o[nt][3] - mu) * rs * gL[nt][3] + bL[nt][3];
            *(uint2*)(dst + nt * 16 + hi * 4) = make_uint2(cvtpk(r0, r1), cvtpk(r2, r3));
        }
    }
}

// ---------- 5. column attention reduction, hpT -> stats ----------
__global__ __launch_bounds__(512) void k_col_red(
        const unsigned short* __restrict__ xb, const unsigned short* __restrict__ wkf,
        const unsigned short* __restrict__ wvf, const float* __restrict__ bk,
        const float* __restrict__ bv, const float* __restrict__ wp,
        float* __restrict__ stats) {
    __shared__ float redK[8][64];
    __shared__ float redV[8][64];
    __shared__ float kvfin[64];

    const int tid = threadIdx.x, lane = tid & 63, w8 = tid >> 6;
    const int t = lane & 15, hi = lane >> 4;
    const int slice = blockIdx.x;                  // b*L + l
    const size_t base = (size_t)slice * P_ * 64;

    short8 wkfr[4][2], wvfr[4][2];
    #pragma unroll
    for (int nt = 0; nt < 4; nt++)
        #pragma unroll
        for (int s = 0; s < 2; s++) {
            wkfr[nt][s] = *(const short8*)(wkf + ((size_t)((nt*2+s)*64 + lane)) * 8);
            wvfr[nt][s] = *(const short8*)(wvf + ((size_t)((nt*2+s)*64 + lane)) * 8);
        }
    f32x4 bkL[4], bvL[4];
    #pragma unroll
    for (int nt = 0; nt < 4; nt++) {
        bkL[nt] = *(const f32x4*)(bk + nt * 16 + hi * 4);
        bvL[nt] = *(const f32x4*)(bv + nt * 16 + hi * 4);
    }

    float ks[4][4] = {}, kv[4][4] = {};
    #pragma unroll 1
    for (int tile = w8; tile < 49; tile += 8) {
        int tok = tile * 16 + t;
        bool valid = tok < P_;
        int tokc = valid ? tok : (P_ - 1);
        const unsigned short* src = xb + base + (size_t)tokc * 64;
        short8 xf[2];
        #pragma unroll
        for (int s = 0; s < 2; s++)
            xf[s] = *(const short8*)(src + s * 32 + hi * 8);
        f32x4 aK[4], aV[4];
        #pragma unroll
        for (int nt = 0; nt < 4; nt++) { aK[nt] = (f32x4){0,0,0,0}; aV[nt] = (f32x4){0,0,0,0}; }
        __builtin_amdgcn_s_setprio(1);
        #pragma unroll
        for (int nt = 0; nt < 4; nt++)
            #pragma unroll
            for (int s = 0; s < 2; s++) {
                aK[nt] = __builtin_amdgcn_mfma_f32_16x16x32_bf16(wkfr[nt][s], xf[s], aK[nt], 0, 0, 0);
                aV[nt] = __builtin_amdgcn_mfma_f32_16x16x32_bf16(wvfr[nt][s], xf[s], aV[nt], 0, 0, 0);
            }
        __builtin_amdgcn_s_setprio(0);
        #pragma unroll
        for (int nt = 0; nt < 4; nt++) {
            float kk[4], vv[4];
            #pragma unroll
            for (int r = 0; r < 4; r++) {
                kk[r] = valid ? elup1(aK[nt][r] + bkL[nt][r]) : 0.0f;
                vv[r] = valid ? (aV[nt][r] + bvL[nt][r]) : 0.0f;
            }
            float sp = kk[0] + kk[1] + kk[2] + kk[3];
            sp += __shfl_xor(sp, 16, 64);
            sp += __shfl_xor(sp, 32, 64);
            #pragma unroll
            for (int r = 0; r < 4; r++) { ks[nt][r] += kk[r]; kv[nt][r] += sp * vv[r]; }
        }
    }

    #pragma unroll
    for (int nt = 0; nt < 4; nt++)
        #pragma unroll
        for (int r = 0; r < 4; r++) {
            #pragma unroll
            for (int m = 1; m < 16; m <<= 1) {
                ks[nt][r] += __shfl_xor(ks[nt][r], m, 64);
                kv[nt][r] += __shfl_xor(kv[nt][r], m, 64);
            }
        }
    if (t == 0) {
        #pragma unroll
        for (int nt = 0; nt < 4; nt++)
            #pragma unroll
            for (int r = 0; r < 4; r++) {
                redK[w8][nt * 16 + hi * 4 + r] = ks[nt][r];
                redV[w8][nt * 16 + hi * 4 + r] = kv[nt][r];
            }
    }
    __syncthreads();
    if (tid < 64) {
        float a = 0.0f, b2 = 0.0f;
        #pragma unroll
        for (int w = 0; w < 8; w++) { a += redK[w][tid]; b2 += redV[w][tid]; }
        stats[(size_t)slice * 320 + tid] = a;    // ksum
        kvfin[tid] = b2;
    }
    __syncthreads();
    if (tid < 256) {
        int c = tid & 63, n = tid >> 6;
        const float* wpr = wp + c * 64 + n * 16;
        float s = 0.0f;
        #pragma unroll
        for (int e = 0; e < 16; e++) s = fmaf(kvfin[n * 16 + e], wpr[e], s);
        stats[(size_t)slice * 320 + 64 + c * 4 + n] = s;   // Wkv[c][n]
    }
}

// ---------- 6. FUSED col-attn map + FFN, 3 tiles/wave (r10-validated + setprio) ----------
template <int MODE>
__global__ __launch_bounds__(256, 2) void k_cmap_ffn3(
        const unsigned short* __restrict__ hpT, unsigned short* __restrict__ hp,
        const unsigned short* __restrict__ wqf,
        const float* __restrict__ bq, const float* __restrict__ bpv,
        const float* __restrict__ stats,
        const unsigned short* __restrict__ w1s, const float* __restrict__ f1b,
        const unsigned short* __restrict__ w2s, const float* __restrict__ f2b,
        const float* __restrict__ lng, const float* __restrict__ lnb,
        const float* __restrict__ wout, const float* __restrict__ bout,
        float* __restrict__ out) {
    __shared__ __align__(16) unsigned char G2[4][3][4096];  // [wave][tile][]
    __shared__ float sstat[320];

    const int tid = threadIdx.x, lane = tid & 63, wv = tid >> 6;
    const int t = lane & 15, hi = lane >> 4;
    const int slice = blockIdx.x / 5, tb = blockIdx.x % 5;
    const int bb = slice >> 9, ll = slice & 511;
    const size_t base = (size_t)slice * P_ * 64;

    for (int i = tid; i < 320; i += 256) sstat[i] = stats[(size_t)slice * 320 + i];
    __syncthreads();
    if (tb * 12 + wv >= 49) return;   // whole wave invalid (only tb==4, wv>=1)

    short8 wqfr[4][2];
    #pragma unroll
    for (int nt = 0; nt < 4; nt++)
        #pragma unroll
        for (int s = 0; s < 2; s++)
            wqfr[nt][s] = *(const short8*)(wqf + ((size_t)((nt*2+s)*64 + lane)) * 8);
    f32x4 bqL[4], bpL[4], gL[4], bL[4], f2bL[4];
    #pragma unroll
    for (int nt = 0; nt < 4; nt++) {
        bqL[nt]  = *(const f32x4*)(bq  + nt * 16 + hi * 4);
        bpL[nt]  = *(const f32x4*)(bpv + nt * 16 + hi * 4);
        gL[nt]   = *(const f32x4*)(lng + nt * 16 + hi * 4);
        bL[nt]   = *(const f32x4*)(lnb + nt * 16 + hi * 4);
        f2bL[nt] = *(const f32x4*)(f2b + nt * 16 + hi * 4);
    }

    uint32_t pw[3][8];          // packed LN-out bf16 pairs [tile][nt*2 + half]
    short8 xb2A[3][2];
    bool validA[3];
    int pcA[3];

    // ---- map phase, 3 tiles (independent -> ILP) ----
    #pragma unroll
    for (int tt = 0; tt < 3; tt++) {
        int slot = tb * 12 + tt * 4 + wv;
        int slotc = (slot < 49) ? slot : 48;
        int p = slotc * 16 + t;
        bool valid = (slot < 49) && (p < P_);
        int pc = (p < P_) ? p : P_ - 1;
        validA[tt] = valid; pcA[tt] = pc;
        const unsigned short* src = hpT + base + (size_t)pc * 64;

        short8 xf[2];
        #pragma unroll
        for (int s = 0; s < 2; s++)
            xf[s] = *(const short8*)(src + s * 32 + hi * 8);
        f32x4 aQ[4];
        #pragma unroll
        for (int nt = 0; nt < 4; nt++) aQ[nt] = (f32x4){0,0,0,0};
        __builtin_amdgcn_s_setprio(1);
        #pragma unroll
        for (int nt = 0; nt < 4; nt++)
            #pragma unroll
            for (int s = 0; s < 2; s++)
                aQ[nt] = __builtin_amdgcn_mfma_f32_16x16x32_bf16(wqfr[nt][s], xf[s], aQ[nt], 0, 0, 0);
        __builtin_amdgcn_s_setprio(0);
        float z[4];
        #pragma unroll
        for (int nt = 0; nt < 4; nt++) {
            f32x4 kS = *(const f32x4*)(sstat + nt * 16 + hi * 4);
            float d = 0.0f;
            #pragma unroll
            for (int r = 0; r < 4; r++)
                d = fmaf(elup1(aQ[nt][r] + bqL[nt][r]), kS[r], d);
            d += __shfl_xor(d, 16, 64);
            d += __shfl_xor(d, 32, 64);
            z[nt] = 1.0f / (d + 1e-6f);
        }
        float vv[4][4];
        float s1 = 0.0f, s2 = 0.0f;
        #pragma unroll
        for (int nt = 0; nt < 4; nt++) {
            us4 xr4 = *(const us4*)(src + nt * 16 + hi * 4);
            #pragma unroll
            for (int r = 0; r < 4; r++) {
                int ch = nt * 16 + hi * 4 + r;
                f32x4 wv4 = *(const f32x4*)(sstat + 64 + ch * 4);
                float val = z[0] * wv4[0] + z[1] * wv4[1] + z[2] * wv4[2] + z[3] * wv4[3]
                          + bpL[nt][r] + bf2f(xr4[r]);
                vv[nt][r] = val;
                s1 += val; s2 += val * val;
            }
        }
        s1 += __shfl_xor(s1, 16, 64);  s1 += __shfl_xor(s1, 32, 64);
        s2 += __shfl_xor(s2, 16, 64);  s2 += __shfl_xor(s2, 32, 64);
        float mu  = s1 * (1.0f / 64.0f);
        float var = s2 * (1.0f / 64.0f) - mu * mu;
        float rs  = rsqrtf(var + 1e-5f);
        #pragma unroll
        for (int nt = 0; nt < 4; nt++) {
            float r0 = (vv[nt][0] - mu) * rs * gL[nt][0] + bL[nt][0];
            float r1 = (vv[nt][1] - mu) * rs * gL[nt][1] + bL[nt][1];
            float r2 = (vv[nt][2] - mu) * rs * gL[nt][2] + bL[nt][2];
            float r3 = (vv[nt][3] - mu) * rs * gL[nt][3] + bL[nt][3];
            pw[tt][nt * 2]     = cvtpk(r0, r1);
            pw[tt][nt * 2 + 1] = cvtpk(r2, r3);
        }

        // repack y -> B-frags via per-wave-per-tile LDS region (first 2KB of
        // G2[wv][tt]); consumed into registers before FFN writes the same region
        unsigned char* yw = &G2[wv][tt][0];
        #pragma unroll
        for (int nt = 0; nt < 4; nt++) {
            uint32_t ch0 = nt * 16 + hi * 4;
            uint32_t boff = (uint32_t)t * 128 + ((ch0 >> 3) ^ (uint32_t)(t & 7)) * 16 + (ch0 & 7) * 2;
            *(uint2*)(yw + boff) = make_uint2(pw[tt][nt * 2], pw[tt][nt * 2 + 1]);
        }
        #pragma unroll
        for (int s = 0; s < 2; s++)
            xb2A[tt][s] = *(short8*)(yw + (uint32_t)t * 128 +
                                     (((uint32_t)(s * 4 + hi)) ^ (uint32_t)(t & 7)) * 16);
    }

    // ---- FFN: each weight fragment load feeds 3 tiles (half-split, 16 MFMA spans) ----
    f32x4 acc2A[3][4];
    #pragma unroll
    for (int tt = 0; tt < 3; tt++)
        #pragma unroll
        for (int n2 = 0; n2 < 4; n2++) acc2A[tt][n2] = f2bL[n2];

    #pragma unroll
    for (int half = 0; half < 2; half++) {
        #pragma unroll
        for (int ntl = 0; ntl < 8; ntl++) {
            int nt = half * 8 + ntl;
            f32x4 b1 = *(const f32x4*)(f1b + nt * 16 + hi * 4);
            f32x4 accA[3] = { b1, b1, b1 };
            __builtin_amdgcn_s_setprio(1);
            #pragma unroll
            for (int s = 0; s < 2; s++) {
                short8 wf = *(const short8*)(w1s + ((size_t)(nt * 2 + s) * 64 + lane) * 8);
                accA[0] = __builtin_amdgcn_mfma_f32_16x16x32_bf16(wf, xb2A[0][s], accA[0], 0, 0, 0);
                accA[1] = __builtin_amdgcn_mfma_f32_16x16x32_bf16(wf, xb2A[1][s], accA[1], 0, 0, 0);
                accA[2] = __builtin_amdgcn_mfma_f32_16x16x32_bf16(wf, xb2A[2][s], accA[2], 0, 0, 0);
            }
            __builtin_amdgcn_s_setprio(0);
            uint32_t woff = ((uint32_t)(ntl * 32 + hi * 8)) ^ ((uint32_t)(t & 7) << 4);
            #pragma unroll
            for (int tt = 0; tt < 3; tt++) {
                uint32_t p0 = cvtpk(gelu_fast(accA[tt][0]), gelu_fast(accA[tt][1]));
                uint32_t p1 = cvtpk(gelu_fast(accA[tt][2]), gelu_fast(accA[tt][3]));
                *(uint2*)(&G2[wv][tt][0] + t * 256 + woff) = make_uint2(p0, p1);
            }
        }
        #pragma unroll
        for (int sl = 0; sl < 4; sl++) {
            int s = half * 4 + sl;
            uint32_t roff = ((uint32_t)(sl * 64 + hi * 16)) ^ ((uint32_t)(t & 7) << 4);
            short8 faA[3];
            #pragma unroll
            for (int tt = 0; tt < 3; tt++)
                faA[tt] = *(short8*)(&G2[wv][tt][0] + t * 256 + roff);
            __builtin_amdgcn_s_setprio(1);
            #pragma unroll
            for (int n2 = 0; n2 < 4; n2++) {
                short8 wf = *(const short8*)(w2s + ((size_t)(n2 * 8 + s) * 64 + lane) * 8);
                acc2A[0][n2] = __builtin_amdgcn_mfma_f32_16x16x32_bf16(wf, faA[0], acc2A[0][n2], 0, 0, 0);
                acc2A[1][n2] = __builtin_amdgcn_mfma_f32_16x16x32_bf16(wf, faA[1], acc2A[1][n2], 0, 0, 0);
                acc2A[2][n2] = __builtin_amdgcn_mfma_f32_16x16x32_bf16(wf, faA[2], acc2A[2][n2], 0, 0, 0);
            }
            __builtin_amdgcn_s_setprio(0);
        }
    }

    // ---- epilogue per tile: residual from packed bf16 LN-out ----
    #pragma unroll
    for (int tt = 0; tt < 3; tt++) {
        float vo[4][4];
        float s1 = 0.0f, s2 = 0.0f;
        #pragma unroll
        for (int n2 = 0; n2 < 4; n2++) {
            float y0 = bflo(pw[tt][n2 * 2]);
            float y1 = bfhi(pw[tt][n2 * 2]);
            float y2 = bflo(pw[tt][n2 * 2 + 1]);
            float y3 = bfhi(pw[tt][n2 * 2 + 1]);
            vo[n2][0] = acc2A[tt][n2][0] + y0;
            vo[n2][1] = acc2A[tt][n2][1] + y1;
            vo[n2][2] = acc2A[tt][n2][2] + y2;
            vo[n2][3] = acc2A[tt][n2][3] + y3;
            #pragma unroll
            for (int r = 0; r < 4; r++) { s1 += vo[n2][r]; s2 += vo[n2][r] * vo[n2][r]; }
        }
        if (MODE == 0) {
            s1 += __shfl_xor(s1, 16, 64);  s1 += __shfl_xor(s1, 32, 64);
            s2 += __shfl_xor(s2, 16, 64);  s2 += __shfl_xor(s2, 32, 64);
            float mu  = s1 * (1.0f / 64.0f);
            float var = s2 * (1.0f / 64.0f) - mu * mu;
            float rs  = rsqrtf(var + 1e-5f);
            if (validA[tt]) {
                unsigned short* dst = hp + (((size_t)bb * P_ + pcA[tt]) * L_ + ll) * 64;
                #pragma unroll
                for (int n2 = 0; n2 < 4; n2++) {
                    float r0 = (vo[n2][0] - mu) * rs * gL[n2][0] + bL[n2][0];
                    float r1 = (vo[n2][1] - mu) * rs * gL[n2][1] + bL[n2][1];
                    float r2 = (vo[n2][2] - mu) * rs * gL[n2][2] + bL[n2][2];
                    float r3 = (vo[n2][3] - mu) * rs * gL[n2][3] + bL[n2][3];
                    *(uint2*)(dst + n2 * 16 + hi * 4) = make_uint2(cvtpk(r0, r1), cvtpk(r2, r3));
                }
            }
        } else {
            float part = 0.0f;
            #pragma unroll
            for (int n2 = 0; n2 < 4; n2++) {
                f32x4 w4 = *(const f32x4*)(wout + n2 * 16 + hi * 4);
                #pragma unroll
                for (int r = 0; r < 4; r++)
                    part = fmaf(vo[n2][r], w4[r], part);
            }
            part += __shfl_xor(part, 16, 64);
            part += __shfl_xor(part, 32, 64);
            if (hi == 0 && validA[tt]) {
                float sp = softplus_f(part + bout[0]);
                atomicAdd(out + bb * P_ + pcA[tt], sp * (1.0f / L_));
            }
        }
    }
}

// ---------- launch ----------
extern "C" void kernel_launch(void* const* d_in, const int* in_sizes, int n_in,
                              void* d_out, int out_size, void* d_ws, size_t ws_size,
                              hipStream_t stream) {
    const float* x    = (const float*)d_in[0];
    const float* w_in = (const float*)d_in[1];
    const float* b_in = (const float*)d_in[2];
    const float* g0   = (const float*)d_in[3];
    const float* be0  = (const float*)d_in[4];
    const float* rqw  = (const float*)d_in[5];  const float* rqb = (const float*)d_in[6];
    const float* rkw  = (const float*)d_in[7];  const float* rkb = (const float*)d_in[8];
    const float* rvw  = (const float*)d_in[9];  const float* rvb = (const float*)d_in[10];
    const float* rpw  = (const float*)d_in[11]; const float* rpb = (const float*)d_in[12];
    const float* cqw  = (const float*)d_in[13]; const float* cqb = (const float*)d_in[14];
    const float* ckw  = (const float*)d_in[15]; const float* ckb = (const float*)d_in[16];
    const float* cvw  = (const float*)d_in[17]; const float* cvb = (const float*)d_in[18];
    const float* cpw  = (const float*)d_in[19]; const float* cpb = (const float*)d_in[20];
    const float* lng  = (const float*)d_in[21]; const float* lnb = (const float*)d_in[22];
    const float* f1w  = (const float*)d_in[23]; const float* f1b = (const float*)d_in[24];
    const float* f2w  = (const float*)d_in[25]; const float* f2b = (const float*)d_in[26];
    const float* wout = (const float*)d_in[27]; const float* bout= (const float*)d_in[28];
    float* out = (float*)d_out;

    unsigned short* hp  = (unsigned short*)d_ws;             // NTOK*64 bf16 (row layout)
    unsigned short* hpT = hp + (size_t)NTOK * 64;            // NTOK*64 bf16 (col layout)
    float* h = (float*)(hpT + (size_t)NTOK * 64);            // B*L*S*64 fp32 (dead after gather)
    unsigned short* w1s  = (unsigned short*)h;               // reuse h region after gather
    unsigned short* w2s  = w1s + 2 * 16384;
    unsigned short* qkvf = w2s + 2 * 16384;
    float* stats = (float*)(qkvf + 12 * 4096);               // B*L*320 floats

    hipMemsetAsync(out, 0, (size_t)out_size * sizeof(float), stream);

    k_conv_in<<<(B_ * L_ * S_ * 64) / 256, 256, 0, stream>>>(x, w_in, b_in, h);
    k_gather_ln<<<NTOK / 4, 256, 0, stream>>>(h, g0, be0, hp);
    k_wprep<<<32, 256, 0, stream>>>(f1w, f2w, w1s, w2s);
    k_wprep_qkv<<<24, 256, 0, stream>>>(rqw, rkw, rvw, cqw, ckw, cvw, qkvf);

    for (int i = 0; i < 2; i++) {
        k_row_fused<<<B_ * P_, 512, 0, stream>>>(hp, hpT,
            qkvf + (size_t)(0 + i) * 4096, qkvf + (size_t)(2 + i) * 4096,
            qkvf + (size_t)(4 + i) * 4096,
            rqb + i * 64, rkb + i * 64, rvb + i * 64, rpw + i * 4096, rpb + i * 64,
            lng + i * 64, lnb + i * 64);
        k_col_red<<<B_ * L_, 512, 0, stream>>>(hpT,
            qkvf + (size_t)(8 + i) * 4096, qkvf + (size_t)(10 + i) * 4096,
            ckb + i * 64, cvb + i * 64, cpw + i * 4096, stats);
        if (i == 0) {
            k_cmap_ffn3<0><<<B_ * L_ * 5, 256, 0, stream>>>(hpT, hp,
                qkvf + (size_t)(6 + i) * 4096, cqb + i * 64, cpb + i * 64, stats,
                w1s + (size_t)i * 16384, f1b + i * 256,
                w2s + (size_t)i * 16384, f2b + i * 64,
                lng + i * 64, lnb + i * 64, wout, bout, out);
        } else {
            k_cmap_ffn3<1><<<B_ * L_ * 5, 256, 0, stream>>>(hpT, hp,
                qkvf + (size_t)(6 + i) * 4096, cqb + i * 64, cpb + i * 64, stats,
                w1s + (size_t)i * 16384, f1b + i * 256,
                w2s + (size_t)i * 16384, f2b + i * 64,
                lng + i * 64, lnb + i * 64, wout, bout, out);
        }
    }
}

// Round 15
// 940.594 us; speedup vs baseline: 1.0401x; 1.0401x over previous
//
#include <hip/hip_runtime.h>
#include <math.h>
#include <stdint.h>

#define B_   2
#define S_   40
#define P_   780
#define L_   512
#define C_   64
#define FF_  256
#define NTOK (B_*P_*L_)   // 798720

typedef __attribute__((ext_vector_type(8))) short short8;
typedef __attribute__((ext_vector_type(4))) float f32x4;
typedef __attribute__((ext_vector_type(4))) unsigned short us4;

// ---------- helpers ----------
__device__ __forceinline__ float ln64(float r, float g, float b) {
    float s1 = r, s2 = r * r;
    #pragma unroll
    for (int m = 1; m < 64; m <<= 1) {
        s1 += __shfl_xor(s1, m, 64);
        s2 += __shfl_xor(s2, m, 64);
    }
    float mu  = s1 * (1.0f / 64.0f);
    float var = s2 * (1.0f / 64.0f) - mu * mu;
    return (r - mu) * rsqrtf(var + 1e-5f) * g + b;
}
__device__ __forceinline__ float gelu_fast(float x) {
    float x2 = x * x;
    float u  = x * fmaf(0.044715f, x2, 1.0f);
    float e  = __builtin_amdgcn_exp2f(u * 2.302265106f);
    return x * e * __builtin_amdgcn_rcpf(e + 1.0f);
}
__device__ __forceinline__ float softplus_f(float v) {
    return (v > 20.0f) ? v : log1pf(__expf(v));
}
__device__ __forceinline__ float elup1(float v) {
    return (v > 0.0f) ? v + 1.0f : __expf(v);
}
__device__ __forceinline__ unsigned short f2bf(float f) {
    union { float f; uint32_t u; } cv; cv.f = f;
    uint32_t u = cv.u;
    return (unsigned short)((u + 0x7FFFu + ((u >> 16) & 1u)) >> 16);  // RNE
}
__device__ __forceinline__ float bf2f(unsigned short u) {
    union { uint32_t u; float f; } cv; cv.u = (uint32_t)u << 16; return cv.f;
}
__device__ __forceinline__ float bflo(uint32_t w) {
    union { uint32_t u; float f; } cv; cv.u = w << 16; return cv.f;
}
__device__ __forceinline__ float bfhi(uint32_t w) {
    union { uint32_t u; float f; } cv; cv.u = w & 0xffff0000u; return cv.f;
}
__device__ __forceinline__ uint32_t cvtpk(float a, float b) {
    uint32_t d;
    asm("v_cvt_pk_bf16_f32 %0, %1, %2" : "=v"(d) : "v"(a), "v"(b));
    return d;
}

// ---------- 1. input 1x1 conv 22->64 + ReLU ----------
__global__ void k_conv_in(const float* __restrict__ x, const float* __restrict__ w_in,
                          const float* __restrict__ b_in, float* __restrict__ h) {
    int gid = blockIdx.x * 256 + threadIdx.x;
    int c  = gid & 63;
    int tk = gid >> 6;
    if (tk >= B_ * L_ * S_) return;
    int b = tk / (L_ * S_);
    int r = tk % (L_ * S_);
    int l = r / S_;
    int s = r % S_;
    float acc = b_in[c];
    const float* xb = x + (size_t)b * 22 * L_ * S_ + (size_t)l * S_ + s;
    #pragma unroll
    for (int cc = 0; cc < 22; cc++)
        acc = fmaf(xb[(size_t)cc * L_ * S_], w_in[c * 22 + cc], acc);
    h[gid] = fmaxf(acc, 0.0f);
}

// ---------- 2. seq2pair gather + LN -> hp (bf16, row layout) ----------
__global__ void k_gather_ln(const float* __restrict__ h, const float* __restrict__ g0,
                            const float* __restrict__ be0, unsigned short* __restrict__ hp) {
    int lane = threadIdx.x & 63;
    int wv   = threadIdx.x >> 6;
    int tk = blockIdx.x * 4 + wv;
    if (tk >= NTOK) return;
    int b = tk / (P_ * L_);
    int r = tk % (P_ * L_);
    int p = r / L_;
    int l = r % L_;
    int i = 0, rem = p, cnt = S_ - 1;
    while (rem >= cnt) { rem -= cnt; cnt--; i++; }
    int j = i + 1 + rem;
    const float* hb = h + (((size_t)b * L_ + l) * S_) * 64;
    float v = hb[i * 64 + lane] + hb[j * 64 + lane];
    hp[(size_t)tk * 64 + lane] = f2bf(ln64(v, g0[lane], be0[lane]));
}

// ---------- 3a. QKV weight pre-swizzle into MFMA A-fragment layout (bf16) ----------
__global__ void k_wprep_qkv(const float* __restrict__ rqw, const float* __restrict__ rkw,
                            const float* __restrict__ rvw, const float* __restrict__ cqw,
                            const float* __restrict__ ckw, const float* __restrict__ cvw,
                            unsigned short* __restrict__ qkvf) {
    int g = blockIdx.x * 256 + threadIdx.x;   // < 6144
    if (g >= 6144) return;
    int m = g >> 9, r = g & 511;
    int mat = m >> 1, layer = m & 1;
    int q = r >> 6, lane = r & 63;
    int c = lane & 15, hi = lane >> 4;
    int nt = q >> 1, s = q & 1;
    const float* base;
    switch (mat) {
        case 0: base = rqw; break; case 1: base = rkw; break; case 2: base = rvw; break;
        case 3: base = cqw; break; case 4: base = ckw; break; default: base = cvw; break;
    }
    const float* src = base + layer * 4096 + (nt * 16 + c) * 64 + s * 32 + hi * 8;
    short8 v;
    #pragma unroll
    for (int i = 0; i < 8; i++) v[i] = (short)f2bf(src[i]);
    *(short8*)(qkvf + (size_t)m * 4096 + (size_t)r * 8) = v;
}

// ---------- 3b. FFN weight pre-swizzle ----------
__global__ void k_wprep(const float* __restrict__ f1w, const float* __restrict__ f2w,
                        unsigned short* __restrict__ w1s, unsigned short* __restrict__ w2s) {
    int g = blockIdx.x * 256 + threadIdx.x;   // [0, 8192)
    if (g >= 8192) return;
    int layer = g >> 12;
    int rem   = g & 4095;
    int which = rem >> 11;
    int idx   = rem & 2047;
    int l  = idx & 63;
    int q  = idx >> 6;
    int c  = l & 15, hi = l >> 4;
    const float* src;
    unsigned short* dst;
    if (which == 0) {
        int s = q & 1, nt = q >> 1;
        src = f1w + (size_t)layer * 16384 + (nt * 16 + c) * 64 + s * 32 + hi * 8;
        dst = w1s + (size_t)layer * 16384 + (size_t)idx * 8;
    } else {
        int s = q & 7, nt = q >> 3;
        src = f2w + (size_t)layer * 16384 + (nt * 16 + c) * 256 + s * 32 + hi * 8;
        dst = w2s + (size_t)layer * 16384 + (size_t)idx * 8;
    }
    short8 v;
    #pragma unroll
    for (int i = 0; i < 8; i++) v[i] = (short)f2bf(src[i]);
    *(short8*)dst = v;
}

// ---------- 4. FUSED row attention (reduction + map), hp -> hpT ----------
__global__ __launch_bounds__(512) void k_row_fused(
        const unsigned short* __restrict__ hp, unsigned short* __restrict__ hpT,
        const unsigned short* __restrict__ wqf, const unsigned short* __restrict__ wkf,
        const unsigned short* __restrict__ wvf,
        const float* __restrict__ bq, const float* __restrict__ bk,
        const float* __restrict__ bv, const float* __restrict__ wp,
        const float* __restrict__ bp, const float* __restrict__ lng,
        const float* __restrict__ lnb) {
    __shared__ float redK[8][64];
    __shared__ float redV[8][64];
    __shared__ float kvfin[64];
    __shared__ float sksum[64];
    __shared__ float swkv[256];

    const int tid = threadIdx.x, lane = tid & 63, w8 = tid >> 6;
    const int t = lane & 15, hi = lane >> 4;
    const int slice = blockIdx.x;                  // b*P + p
    const size_t base = (size_t)slice * L_ * 64;

    short8 xkeep[4][2];
    float ks[4][4] = {}, kv[4][4] = {};
    {
        short8 wkfr[4][2], wvfr[4][2];
        #pragma unroll
        for (int nt = 0; nt < 4; nt++)
            #pragma unroll
            for (int s = 0; s < 2; s++) {
                wkfr[nt][s] = *(const short8*)(wkf + ((size_t)((nt*2+s)*64 + lane)) * 8);
                wvfr[nt][s] = *(const short8*)(wvf + ((size_t)((nt*2+s)*64 + lane)) * 8);
            }
        f32x4 bkL[4], bvL[4];
        #pragma unroll
        for (int nt = 0; nt < 4; nt++) {
            bkL[nt] = *(const f32x4*)(bk + nt * 16 + hi * 4);
            bvL[nt] = *(const f32x4*)(bv + nt * 16 + hi * 4);
        }
        #pragma unroll
        for (int it = 0; it < 4; it++) {
            int tok = (w8 + it * 8) * 16 + t;
            const unsigned short* src = hp + base + (size_t)tok * 64;
            #pragma unroll
            for (int s = 0; s < 2; s++)
                xkeep[it][s] = *(const short8*)(src + s * 32 + hi * 8);
            f32x4 aK[4], aV[4];
            #pragma unroll
            for (int nt = 0; nt < 4; nt++) { aK[nt] = (f32x4){0,0,0,0}; aV[nt] = (f32x4){0,0,0,0}; }
            #pragma unroll
            for (int nt = 0; nt < 4; nt++)
                #pragma unroll
                for (int s = 0; s < 2; s++) {
                    aK[nt] = __builtin_amdgcn_mfma_f32_16x16x32_bf16(wkfr[nt][s], xkeep[it][s], aK[nt], 0, 0, 0);
                    aV[nt] = __builtin_amdgcn_mfma_f32_16x16x32_bf16(wvfr[nt][s], xkeep[it][s], aV[nt], 0, 0, 0);
                }
            #pragma unroll
            for (int nt = 0; nt < 4; nt++) {
                float kk[4], vv[4];
                #pragma unroll
                for (int r = 0; r < 4; r++) {
                    kk[r] = elup1(aK[nt][r] + bkL[nt][r]);
                    vv[r] = aV[nt][r] + bvL[nt][r];
                }
                float sp = kk[0] + kk[1] + kk[2] + kk[3];
                sp += __shfl_xor(sp, 16, 64);
                sp += __shfl_xor(sp, 32, 64);
                #pragma unroll
                for (int r = 0; r < 4; r++) { ks[nt][r] += kk[r]; kv[nt][r] += sp * vv[r]; }
            }
        }
    }
    #pragma unroll
    for (int nt = 0; nt < 4; nt++)
        #pragma unroll
        for (int r = 0; r < 4; r++) {
            #pragma unroll
            for (int m = 1; m < 16; m <<= 1) {
                ks[nt][r] += __shfl_xor(ks[nt][r], m, 64);
                kv[nt][r] += __shfl_xor(kv[nt][r], m, 64);
            }
        }
    if (t == 0) {
        #pragma unroll
        for (int nt = 0; nt < 4; nt++)
            #pragma unroll
            for (int r = 0; r < 4; r++) {
                redK[w8][nt * 16 + hi * 4 + r] = ks[nt][r];
                redV[w8][nt * 16 + hi * 4 + r] = kv[nt][r];
            }
    }
    __syncthreads();
    if (tid < 64) {
        float a = 0.0f, b2 = 0.0f;
        #pragma unroll
        for (int w = 0; w < 8; w++) { a += redK[w][tid]; b2 += redV[w][tid]; }
        sksum[tid] = a;
        kvfin[tid] = b2;
    }
    __syncthreads();
    if (tid < 256) {
        int c = tid & 63, n = tid >> 6;
        const float* wpr = wp + c * 64 + n * 16;
        float s = 0.0f;
        #pragma unroll
        for (int e = 0; e < 16; e++) s = fmaf(kvfin[n * 16 + e], wpr[e], s);
        swkv[c * 4 + n] = s;
    }
    __syncthreads();

    short8 wqfr[4][2];
    #pragma unroll
    for (int nt = 0; nt < 4; nt++)
        #pragma unroll
        for (int s = 0; s < 2; s++)
            wqfr[nt][s] = *(const short8*)(wqf + ((size_t)((nt*2+s)*64 + lane)) * 8);
    f32x4 bqL[4], bpL[4], gL[4], bL[4];
    #pragma unroll
    for (int nt = 0; nt < 4; nt++) {
        bqL[nt] = *(const f32x4*)(bq + nt * 16 + hi * 4);
        bpL[nt] = *(const f32x4*)(bp + nt * 16 + hi * 4);
        gL[nt]  = *(const f32x4*)(lng + nt * 16 + hi * 4);
        bL[nt]  = *(const f32x4*)(lnb + nt * 16 + hi * 4);
    }
    const int bb = slice / P_, pp = slice - bb * P_;

    #pragma unroll
    for (int it = 0; it < 4; it++) {
        int tok = (w8 + it * 8) * 16 + t;
        f32x4 aQ[4];
        #pragma unroll
        for (int nt = 0; nt < 4; nt++) aQ[nt] = (f32x4){0,0,0,0};
        #pragma unroll
        for (int nt = 0; nt < 4; nt++)
            #pragma unroll
            for (int s = 0; s < 2; s++)
                aQ[nt] = __builtin_amdgcn_mfma_f32_16x16x32_bf16(wqfr[nt][s], xkeep[it][s], aQ[nt], 0, 0, 0);
        float z[4];
        #pragma unroll
        for (int nt = 0; nt < 4; nt++) {
            f32x4 kS = *(const f32x4*)(sksum + nt * 16 + hi * 4);
            float d = 0.0f;
            #pragma unroll
            for (int r = 0; r < 4; r++)
                d = fmaf(elup1(aQ[nt][r] + bqL[nt][r]), kS[r], d);
            d += __shfl_xor(d, 16, 64);
            d += __shfl_xor(d, 32, 64);
            z[nt] = 1.0f / (d + 1e-6f);
        }
        const unsigned short* srcr = hp + base + (size_t)tok * 64;
        float o[4][4];
        float s1 = 0.0f, s2 = 0.0f;
        #pragma unroll
        for (int nt = 0; nt < 4; nt++) {
            us4 xr4 = *(const us4*)(srcr + nt * 16 + hi * 4);
            #pragma unroll
            for (int r = 0; r < 4; r++) {
                int ch = nt * 16 + hi * 4 + r;
                f32x4 wv4 = *(const f32x4*)(swkv + ch * 4);
                float val = z[0] * wv4[0] + z[1] * wv4[1] + z[2] * wv4[2] + z[3] * wv4[3]
                          + bpL[nt][r] + bf2f(xr4[r]);
                o[nt][r] = val;
                s1 += val; s2 += val * val;
            }
        }
        s1 += __shfl_xor(s1, 16, 64);  s1 += __shfl_xor(s1, 32, 64);
        s2 += __shfl_xor(s2, 16, 64);  s2 += __shfl_xor(s2, 32, 64);
        float mu  = s1 * (1.0f / 64.0f);
        float var = s2 * (1.0f / 64.0f) - mu * mu;
        float rs  = rsqrtf(var + 1e-5f);
        unsigned short* dst = hpT + (((size_t)bb * L_ + tok) * P_ + pp) * 64;
        #pragma unroll
        for (int nt = 0; nt < 4; nt++) {
            float r0 = (o[nt][0] - mu) * rs * gL[nt][0] + bL[nt][0];
            float r1 = (o[nt][1] - mu) * rs * gL[nt][1] + bL[nt][1];
            float r2 = (o[nt][2] - mu) * rs * gL[nt][2] + bL[nt][2];
            float r3 = (o[nt][3] - mu) * rs * gL[nt][3] + bL[nt][3];
            *(uint2*)(dst + nt * 16 + hi * 4) = make_uint2(cvtpk(r0, r1), cvtpk(r2, r3));
        }
    }
}

// ---------- 5. column attention reduction, hpT -> stats ----------
__global__ __launch_bounds__(512) void k_col_red(
        const unsigned short* __restrict__ xb, const unsigned short* __restrict__ wkf,
        const unsigned short* __restrict__ wvf, const float* __restrict__ bk,
        const float* __restrict__ bv, const float* __restrict__ wp,
        float* __restrict__ stats) {
    __shared__ float redK[8][64];
    __shared__ float redV[8][64];
    __shared__ float kvfin[64];

    const int tid = threadIdx.x, lane = tid & 63, w8 = tid >> 6;
    const int t = lane & 15, hi = lane >> 4;
    const int slice = blockIdx.x;                  // b*L + l
    const size_t base = (size_t)slice * P_ * 64;

    short8 wkfr[4][2], wvfr[4][2];
    #pragma unroll
    for (int nt = 0; nt < 4; nt++)
        #pragma unroll
        for (int s = 0; s < 2; s++) {
            wkfr[nt][s] = *(const short8*)(wkf + ((size_t)((nt*2+s)*64 + lane)) * 8);
            wvfr[nt][s] = *(const short8*)(wvf + ((size_t)((nt*2+s)*64 + lane)) * 8);
        }
    f32x4 bkL[4], bvL[4];
    #pragma unroll
    for (int nt = 0; nt < 4; nt++) {
        bkL[nt] = *(const f32x4*)(bk + nt * 16 + hi * 4);
        bvL[nt] = *(const f32x4*)(bv + nt * 16 + hi * 4);
    }

    float ks[4][4] = {}, kv[4][4] = {};
    #pragma unroll 1
    for (int tile = w8; tile < 49; tile += 8) {
        int tok = tile * 16 + t;
        bool valid = tok < P_;
        int tokc = valid ? tok : (P_ - 1);
        const unsigned short* src = xb + base + (size_t)tokc * 64;
        short8 xf[2];
        #pragma unroll
        for (int s = 0; s < 2; s++)
            xf[s] = *(const short8*)(src + s * 32 + hi * 8);
        f32x4 aK[4], aV[4];
        #pragma unroll
        for (int nt = 0; nt < 4; nt++) { aK[nt] = (f32x4){0,0,0,0}; aV[nt] = (f32x4){0,0,0,0}; }
        #pragma unroll
        for (int nt = 0; nt < 4; nt++)
            #pragma unroll
            for (int s = 0; s < 2; s++) {
                aK[nt] = __builtin_amdgcn_mfma_f32_16x16x32_bf16(wkfr[nt][s], xf[s], aK[nt], 0, 0, 0);
                aV[nt] = __builtin_amdgcn_mfma_f32_16x16x32_bf16(wvfr[nt][s], xf[s], aV[nt], 0, 0, 0);
            }
        #pragma unroll
        for (int nt = 0; nt < 4; nt++) {
            float kk[4], vv[4];
            #pragma unroll
            for (int r = 0; r < 4; r++) {
                kk[r] = valid ? elup1(aK[nt][r] + bkL[nt][r]) : 0.0f;
                vv[r] = valid ? (aV[nt][r] + bvL[nt][r]) : 0.0f;
            }
            float sp = kk[0] + kk[1] + kk[2] + kk[3];
            sp += __shfl_xor(sp, 16, 64);
            sp += __shfl_xor(sp, 32, 64);
            #pragma unroll
            for (int r = 0; r < 4; r++) { ks[nt][r] += kk[r]; kv[nt][r] += sp * vv[r]; }
        }
    }

    #pragma unroll
    for (int nt = 0; nt < 4; nt++)
        #pragma unroll
        for (int r = 0; r < 4; r++) {
            #pragma unroll
            for (int m = 1; m < 16; m <<= 1) {
                ks[nt][r] += __shfl_xor(ks[nt][r], m, 64);
                kv[nt][r] += __shfl_xor(kv[nt][r], m, 64);
            }
        }
    if (t == 0) {
        #pragma unroll
        for (int nt = 0; nt < 4; nt++)
            #pragma unroll
            for (int r = 0; r < 4; r++) {
                redK[w8][nt * 16 + hi * 4 + r] = ks[nt][r];
                redV[w8][nt * 16 + hi * 4 + r] = kv[nt][r];
            }
    }
    __syncthreads();
    if (tid < 64) {
        float a = 0.0f, b2 = 0.0f;
        #pragma unroll
        for (int w = 0; w < 8; w++) { a += redK[w][tid]; b2 += redV[w][tid]; }
        stats[(size_t)slice * 320 + tid] = a;    // ksum
        kvfin[tid] = b2;
    }
    __syncthreads();
    if (tid < 256) {
        int c = tid & 63, n = tid >> 6;
        const float* wpr = wp + c * 64 + n * 16;
        float s = 0.0f;
        #pragma unroll
        for (int e = 0; e < 16; e++) s = fmaf(kvfin[n * 16 + e], wpr[e], s);
        stats[(size_t)slice * 320 + 64 + c * 4 + n] = s;   // Wkv[c][n]
    }
}

// ---------- 6. FUSED col-attn map + FFN, 3 tiles/wave (r10-validated) ----------
template <int MODE>
__global__ __launch_bounds__(256, 2) void k_cmap_ffn3(
        const unsigned short* __restrict__ hpT, unsigned short* __restrict__ hp,
        const unsigned short* __restrict__ wqf,
        const float* __restrict__ bq, const float* __restrict__ bpv,
        const float* __restrict__ stats,
        const unsigned short* __restrict__ w1s, const float* __restrict__ f1b,
        const unsigned short* __restrict__ w2s, const float* __restrict__ f2b,
        const float* __restrict__ lng, const float* __restrict__ lnb,
        const float* __restrict__ wout, const float* __restrict__ bout,
        float* __restrict__ out) {
    __shared__ __align__(16) unsigned char G2[4][3][4096];  // [wave][tile][]
    __shared__ float sstat[320];

    const int tid = threadIdx.x, lane = tid & 63, wv = tid >> 6;
    const int t = lane & 15, hi = lane >> 4;
    const int slice = blockIdx.x / 5, tb = blockIdx.x % 5;
    const int bb = slice >> 9, ll = slice & 511;
    const size_t base = (size_t)slice * P_ * 64;

    for (int i = tid; i < 320; i += 256) sstat[i] = stats[(size_t)slice * 320 + i];
    __syncthreads();
    if (tb * 12 + wv >= 49) return;   // whole wave invalid (only tb==4, wv>=1)

    short8 wqfr[4][2];
    #pragma unroll
    for (int nt = 0; nt < 4; nt++)
        #pragma unroll
        for (int s = 0; s < 2; s++)
            wqfr[nt][s] = *(const short8*)(wqf + ((size_t)((nt*2+s)*64 + lane)) * 8);
    f32x4 bqL[4], bpL[4], gL[4], bL[4], f2bL[4];
    #pragma unroll
    for (int nt = 0; nt < 4; nt++) {
        bqL[nt]  = *(const f32x4*)(bq  + nt * 16 + hi * 4);
        bpL[nt]  = *(const f32x4*)(bpv + nt * 16 + hi * 4);
        gL[nt]   = *(const f32x4*)(lng + nt * 16 + hi * 4);
        bL[nt]   = *(const f32x4*)(lnb + nt * 16 + hi * 4);
        f2bL[nt] = *(const f32x4*)(f2b + nt * 16 + hi * 4);
    }

    uint32_t pw[3][8];          // packed LN-out bf16 pairs [tile][nt*2 + half]
    short8 xb2A[3][2];
    bool validA[3];
    int pcA[3];

    // ---- map phase, 3 tiles (independent -> ILP) ----
    #pragma unroll
    for (int tt = 0; tt < 3; tt++) {
        int slot = tb * 12 + tt * 4 + wv;
        int slotc = (slot < 49) ? slot : 48;
        int p = slotc * 16 + t;
        bool valid = (slot < 49) && (p < P_);
        int pc = (p < P_) ? p : P_ - 1;
        validA[tt] = valid; pcA[tt] = pc;
        const unsigned short* src = hpT + base + (size_t)pc * 64;

        short8 xf[2];
        #pragma unroll
        for (int s = 0; s < 2; s++)
            xf[s] = *(const short8*)(src + s * 32 + hi * 8);
        f32x4 aQ[4];
        #pragma unroll
        for (int nt = 0; nt < 4; nt++) aQ[nt] = (f32x4){0,0,0,0};
        #pragma unroll
        for (int nt = 0; nt < 4; nt++)
            #pragma unroll
            for (int s = 0; s < 2; s++)
                aQ[nt] = __builtin_amdgcn_mfma_f32_16x16x32_bf16(wqfr[nt][s], xf[s], aQ[nt], 0, 0, 0);
        float z[4];
        #pragma unroll
        for (int nt = 0; nt < 4; nt++) {
            f32x4 kS = *(const f32x4*)(sstat + nt * 16 + hi * 4);
            float d = 0.0f;
            #pragma unroll
            for (int r = 0; r < 4; r++)
                d = fmaf(elup1(aQ[nt][r] + bqL[nt][r]), kS[r], d);
            d += __shfl_xor(d, 16, 64);
            d += __shfl_xor(d, 32, 64);
            z[nt] = 1.0f / (d + 1e-6f);
        }
        float vv[4][4];
        float s1 = 0.0f, s2 = 0.0f;
        #pragma unroll
        for (int nt = 0; nt < 4; nt++) {
            us4 xr4 = *(const us4*)(src + nt * 16 + hi * 4);
            #pragma unroll
            for (int r = 0; r < 4; r++) {
                int ch = nt * 16 + hi * 4 + r;
                f32x4 wv4 = *(const f32x4*)(sstat + 64 + ch * 4);
                float val = z[0] * wv4[0] + z[1] * wv4[1] + z[2] * wv4[2] + z[3] * wv4[3]
                          + bpL[nt][r] + bf2f(xr4[r]);
                vv[nt][r] = val;
                s1 += val; s2 += val * val;
            }
        }
        s1 += __shfl_xor(s1, 16, 64);  s1 += __shfl_xor(s1, 32, 64);
        s2 += __shfl_xor(s2, 16, 64);  s2 += __shfl_xor(s2, 32, 64);
        float mu  = s1 * (1.0f / 64.0f);
        float var = s2 * (1.0f / 64.0f) - mu * mu;
        float rs  = rsqrtf(var + 1e-5f);
        #pragma unroll
        for (int nt = 0; nt < 4; nt++) {
            float r0 = (vv[nt][0] - mu) * rs * gL[nt][0] + bL[nt][0];
            float r1 = (vv[nt][1] - mu) * rs * gL[nt][1] + bL[nt][1];
            float r2 = (vv[nt][2] - mu) * rs * gL[nt][2] + bL[nt][2];
            float r3 = (vv[nt][3] - mu) * rs * gL[nt][3] + bL[nt][3];
            pw[tt][nt * 2]     = cvtpk(r0, r1);
            pw[tt][nt * 2 + 1] = cvtpk(r2, r3);
        }

        // repack y -> B-frags via per-wave-per-tile LDS region (first 2KB of
        // G2[wv][tt]); consumed into registers before FFN writes the same region
        unsigned char* yw = &G2[wv][tt][0];
        #pragma unroll
        for (int nt = 0; nt < 4; nt++) {
            uint32_t ch0 = nt * 16 + hi * 4;
            uint32_t boff = (uint32_t)t * 128 + ((ch0 >> 3) ^ (uint32_t)(t & 7)) * 16 + (ch0 & 7) * 2;
            *(uint2*)(yw + boff) = make_uint2(pw[tt][nt * 2], pw[tt][nt * 2 + 1]);
        }
        #pragma unroll
        for (int s = 0; s < 2; s++)
            xb2A[tt][s] = *(short8*)(yw + (uint32_t)t * 128 +
                                     (((uint32_t)(s * 4 + hi)) ^ (uint32_t)(t & 7)) * 16);
    }

    // ---- FFN: each weight fragment load feeds 3 tiles (half-split, 16 MFMA spans) ----
    f32x4 acc2A[3][4];
    #pragma unroll
    for (int tt = 0; tt < 3; tt++)
        #pragma unroll
        for (int n2 = 0; n2 < 4; n2++) acc2A[tt][n2] = f2bL[n2];

    #pragma unroll
    for (int half = 0; half < 2; half++) {
        #pragma unroll
        for (int ntl = 0; ntl < 8; ntl++) {
            int nt = half * 8 + ntl;
            f32x4 b1 = *(const f32x4*)(f1b + nt * 16 + hi * 4);
            f32x4 accA[3] = { b1, b1, b1 };
            #pragma unroll
            for (int s = 0; s < 2; s++) {
                short8 wf = *(const short8*)(w1s + ((size_t)(nt * 2 + s) * 64 + lane) * 8);
                accA[0] = __builtin_amdgcn_mfma_f32_16x16x32_bf16(wf, xb2A[0][s], accA[0], 0, 0, 0);
                accA[1] = __builtin_amdgcn_mfma_f32_16x16x32_bf16(wf, xb2A[1][s], accA[1], 0, 0, 0);
                accA[2] = __builtin_amdgcn_mfma_f32_16x16x32_bf16(wf, xb2A[2][s], accA[2], 0, 0, 0);
            }
            uint32_t woff = ((uint32_t)(ntl * 32 + hi * 8)) ^ ((uint32_t)(t & 7) << 4);
            #pragma unroll
            for (int tt = 0; tt < 3; tt++) {
                uint32_t p0 = cvtpk(gelu_fast(accA[tt][0]), gelu_fast(accA[tt][1]));
                uint32_t p1 = cvtpk(gelu_fast(accA[tt][2]), gelu_fast(accA[tt][3]));
                *(uint2*)(&G2[wv][tt][0] + t * 256 + woff) = make_uint2(p0, p1);
            }
        }
        #pragma unroll
        for (int sl = 0; sl < 4; sl++) {
            int s = half * 4 + sl;
            uint32_t roff = ((uint32_t)(sl * 64 + hi * 16)) ^ ((uint32_t)(t & 7) << 4);
            short8 faA[3];
            #pragma unroll
            for (int tt = 0; tt < 3; tt++)
                faA[tt] = *(short8*)(&G2[wv][tt][0] + t * 256 + roff);
            #pragma unroll
            for (int n2 = 0; n2 < 4; n2++) {
                short8 wf = *(const short8*)(w2s + ((size_t)(n2 * 8 + s) * 64 + lane) * 8);
                acc2A[0][n2] = __builtin_amdgcn_mfma_f32_16x16x32_bf16(wf, faA[0], acc2A[0][n2], 0, 0, 0);
                acc2A[1][n2] = __builtin_amdgcn_mfma_f32_16x16x32_bf16(wf, faA[1], acc2A[1][n2], 0, 0, 0);
                acc2A[2][n2] = __builtin_amdgcn_mfma_f32_16x16x32_bf16(wf, faA[2], acc2A[2][n2], 0, 0, 0);
            }
        }
    }

    // ---- epilogue per tile: residual from packed bf16 LN-out ----
    #pragma unroll
    for (int tt = 0; tt < 3; tt++) {
        float vo[4][4];
        float s1 = 0.0f, s2 = 0.0f;
        #pragma unroll
        for (int n2 = 0; n2 < 4; n2++) {
            float y0 = bflo(pw[tt][n2 * 2]);
            float y1 = bfhi(pw[tt][n2 * 2]);
            float y2 = bflo(pw[tt][n2 * 2 + 1]);
            float y3 = bfhi(pw[tt][n2 * 2 + 1]);
            vo[n2][0] = acc2A[tt][n2][0] + y0;
            vo[n2][1] = acc2A[tt][n2][1] + y1;
            vo[n2][2] = acc2A[tt][n2][2] + y2;
            vo[n2][3] = acc2A[tt][n2][3] + y3;
            #pragma unroll
            for (int r = 0; r < 4; r++) { s1 += vo[n2][r]; s2 += vo[n2][r] * vo[n2][r]; }
        }
        if (MODE == 0) {
            s1 += __shfl_xor(s1, 16, 64);  s1 += __shfl_xor(s1, 32, 64);
            s2 += __shfl_xor(s2, 16, 64);  s2 += __shfl_xor(s2, 32, 64);
            float mu  = s1 * (1.0f / 64.0f);
            float var = s2 * (1.0f / 64.0f) - mu * mu;
            float rs  = rsqrtf(var + 1e-5f);
            if (validA[tt]) {
                unsigned short* dst = hp + (((size_t)bb * P_ + pcA[tt]) * L_ + ll) * 64;
                #pragma unroll
                for (int n2 = 0; n2 < 4; n2++) {
                    float r0 = (vo[n2][0] - mu) * rs * gL[n2][0] + bL[n2][0];
                    float r1 = (vo[n2][1] - mu) * rs * gL[n2][1] + bL[n2][1];
                    float r2 = (vo[n2][2] - mu) * rs * gL[n2][2] + bL[n2][2];
                    float r3 = (vo[n2][3] - mu) * rs * gL[n2][3] + bL[n2][3];
                    *(uint2*)(dst + n2 * 16 + hi * 4) = make_uint2(cvtpk(r0, r1), cvtpk(r2, r3));
                }
            }
        } else {
            float part = 0.0f;
            #pragma unroll
            for (int n2 = 0; n2 < 4; n2++) {
                f32x4 w4 = *(const f32x4*)(wout + n2 * 16 + hi * 4);
                #pragma unroll
                for (int r = 0; r < 4; r++)
                    part = fmaf(vo[n2][r], w4[r], part);
            }
            part += __shfl_xor(part, 16, 64);
            part += __shfl_xor(part, 32, 64);
            if (hi == 0 && validA[tt]) {
                float sp = softplus_f(part + bout[0]);
                atomicAdd(out + bb * P_ + pcA[tt], sp * (1.0f / L_));
            }
        }
    }
}

// ---------- launch ----------
extern "C" void kernel_launch(void* const* d_in, const int* in_sizes, int n_in,
                              void* d_out, int out_size, void* d_ws, size_t ws_size,
                              hipStream_t stream) {
    const float* x    = (const float*)d_in[0];
    const float* w_in = (const float*)d_in[1];
    const float* b_in = (const float*)d_in[2];
    const float* g0   = (const float*)d_in[3];
    const float* be0  = (const float*)d_in[4];
    const float* rqw  = (const float*)d_in[5];  const float* rqb = (const float*)d_in[6];
    const float* rkw  = (const float*)d_in[7];  const float* rkb = (const float*)d_in[8];
    const float* rvw  = (const float*)d_in[9];  const float* rvb = (const float*)d_in[10];
    const float* rpw  = (const float*)d_in[11]; const float* rpb = (const float*)d_in[12];
    const float* cqw  = (const float*)d_in[13]; const float* cqb = (const float*)d_in[14];
    const float* ckw  = (const float*)d_in[15]; const float* ckb = (const float*)d_in[16];
    const float* cvw  = (const float*)d_in[17]; const float* cvb = (const float*)d_in[18];
    const float* cpw  = (const float*)d_in[19]; const float* cpb = (const float*)d_in[20];
    const float* lng  = (const float*)d_in[21]; const float* lnb = (const float*)d_in[22];
    const float* f1w  = (const float*)d_in[23]; const float* f1b = (const float*)d_in[24];
    const float* f2w  = (const float*)d_in[25]; const float* f2b = (const float*)d_in[26];
    const float* wout = (const float*)d_in[27]; const float* bout= (const float*)d_in[28];
    float* out = (float*)d_out;

    unsigned short* hp  = (unsigned short*)d_ws;             // NTOK*64 bf16 (row layout)
    unsigned short* hpT = hp + (size_t)NTOK * 64;            // NTOK*64 bf16 (col layout)
    float* h = (float*)(hpT + (size_t)NTOK * 64);            // B*L*S*64 fp32 (dead after gather)
    unsigned short* w1s  = (unsigned short*)h;               // reuse h region after gather
    unsigned short* w2s  = w1s + 2 * 16384;
    unsigned short* qkvf = w2s + 2 * 16384;
    float* stats = (float*)(qkvf + 12 * 4096);               // B*L*320 floats

    hipMemsetAsync(out, 0, (size_t)out_size * sizeof(float), stream);

    k_conv_in<<<(B_ * L_ * S_ * 64) / 256, 256, 0, stream>>>(x, w_in, b_in, h);
    k_gather_ln<<<NTOK / 4, 256, 0, stream>>>(h, g0, be0, hp);
    k_wprep<<<32, 256, 0, stream>>>(f1w, f2w, w1s, w2s);
    k_wprep_qkv<<<24, 256, 0, stream>>>(rqw, rkw, rvw, cqw, ckw, cvw, qkvf);

    for (int i = 0; i < 2; i++) {
        k_row_fused<<<B_ * P_, 512, 0, stream>>>(hp, hpT,
            qkvf + (size_t)(0 + i) * 4096, qkvf + (size_t)(2 + i) * 4096,
            qkvf + (size_t)(4 + i) * 4096,
            rqb + i * 64, rkb + i * 64, rvb + i * 64, rpw + i * 4096, rpb + i * 64,
            lng + i * 64, lnb + i * 64);
        k_col_red<<<B_ * L_, 512, 0, stream>>>(hpT,
            qkvf + (size_t)(8 + i) * 4096, qkvf + (size_t)(10 + i) * 4096,
            ckb + i * 64, cvb + i * 64, cpw + i * 4096, stats);
        if (i == 0) {
            k_cmap_ffn3<0><<<B_ * L_ * 5, 256, 0, stream>>>(hpT, hp,
                qkvf + (size_t)(6 + i) * 4096, cqb + i * 64, cpb + i * 64, stats,
                w1s + (size_t)i * 16384, f1b + i * 256,
                w2s + (size_t)i * 16384, f2b + i * 64,
                lng + i * 64, lnb + i * 64, wout, bout, out);
        } else {
            k_cmap_ffn3<1><<<B_ * L_ * 5, 256, 0, stream>>>(hpT, hp,
                qkvf + (size_t)(6 + i) * 4096, cqb + i * 64, cpb + i * 64, stats,
                w1s + (size_t)i * 16384, f1b + i * 256,
                w2s + (size_t)i * 16384, f2b + i * 64,
                lng + i * 64, lnb + i * 64, wout, bout, out);
        }
    }
}